// Round 3
// baseline (15844.650 us; speedup 1.0000x reference)
//
#include <hip/hip_runtime.h>
#include <hip/hip_bf16.h>

#define LSEQ 50
#define BATCH 256
#define DIN 256
#define LAT 512
#define HID 1024
#define GSZ 3072
#define ROWSTRIDE 257  // D_IN + 1 (dt channel)

using u16 = unsigned short;

__device__ __forceinline__ float sigmoidf_(float x) { return 1.0f / (1.0f + __expf(-x)); }

__global__ __launch_bounds__(256) void zero_k(float* __restrict__ p, int n) {
  int i = blockIdx.x * 256 + threadIdx.x;
  if (i < n) p[i] = 0.f;
}

// fp32 tiled GEMM: C[M=256 x N] = epilogue(A[256 x K] * B + bias)
// A: fp32 row-major, leading dim lda. ASTRIDED: lda not 4-aligned -> scalar loads.
// B: fp32 weights. BNMAJOR=false: B[k*ldb + n] (mlp_w1/w2).
//                  BNMAJOR=true : B[n*ldb + k] (gru_whh/wih rows).
// EPI: 0 = store acc+bias; 1 = store tanh(acc+bias);
//      2 = C[r,c] += (acc+bias) * dt[t,r]/3  (Euler ODE update)
template<bool ASTRIDED, bool BNMAJOR, int EPI>
__global__ __launch_bounds__(256) void gemm_k(
    const float* __restrict__ A, int lda,
    const float* __restrict__ Bw, int ldb,
    const float* __restrict__ bias,
    float* __restrict__ C, int ldc,
    int K,
    const float* __restrict__ data, int t)
{
  __shared__ float As[16][68];
  __shared__ float Bs[16][68];
  const int tid = threadIdx.x;
  const int tx = tid & 15, ty = tid >> 4;
  const int bn = blockIdx.x * 64;
  const int bm = blockIdx.y * 64;
  const int lm  = tid >> 2;        // 0..63
  const int lk4 = (tid & 3) * 4;   // 0,4,8,12
  const int bkr = tid >> 4;        // 0..15 (k row for k-major B staging)
  const int bn4 = (tid & 15) * 4;

  float acc[4][4];
  #pragma unroll
  for (int i = 0; i < 4; i++)
    #pragma unroll
    for (int j = 0; j < 4; j++) acc[i][j] = 0.f;

  for (int k0 = 0; k0 < K; k0 += 16) {
    __syncthreads();
    // stage A tile (transposed: As[k][m])
    if (ASTRIDED) {
      #pragma unroll
      for (int i = 0; i < 4; i++)
        As[lk4 + i][lm] = A[(size_t)(bm + lm) * lda + k0 + lk4 + i];
    } else {
      float4 a4 = *(const float4*)&A[(size_t)(bm + lm) * lda + k0 + lk4];
      As[lk4 + 0][lm] = a4.x; As[lk4 + 1][lm] = a4.y;
      As[lk4 + 2][lm] = a4.z; As[lk4 + 3][lm] = a4.w;
    }
    // stage B tile (Bs[k][n])
    if (BNMAJOR) {
      float4 b4 = *(const float4*)&Bw[(size_t)(bn + lm) * ldb + k0 + lk4];
      Bs[lk4 + 0][lm] = b4.x; Bs[lk4 + 1][lm] = b4.y;
      Bs[lk4 + 2][lm] = b4.z; Bs[lk4 + 3][lm] = b4.w;
    } else {
      float4 b4 = *(const float4*)&Bw[(size_t)(k0 + bkr) * ldb + bn + bn4];
      Bs[bkr][bn4 + 0] = b4.x; Bs[bkr][bn4 + 1] = b4.y;
      Bs[bkr][bn4 + 2] = b4.z; Bs[bkr][bn4 + 3] = b4.w;
    }
    __syncthreads();
    #pragma unroll
    for (int kk = 0; kk < 16; kk++) {
      float4 av = *(const float4*)&As[kk][ty * 4];
      float4 bv = *(const float4*)&Bs[kk][tx * 4];
      float a[4] = {av.x, av.y, av.z, av.w};
      float b[4] = {bv.x, bv.y, bv.z, bv.w};
      #pragma unroll
      for (int i = 0; i < 4; i++)
        #pragma unroll
        for (int j = 0; j < 4; j++)
          acc[i][j] = fmaf(a[i], b[j], acc[i][j]);
    }
  }
  const int row0 = bm + ty * 4;
  const int col0 = bn + tx * 4;
  #pragma unroll
  for (int i = 0; i < 4; i++) {
    const int r = row0 + i;
    float dscale = 0.f;
    if (EPI == 2)
      dscale = data[(size_t)(t * BATCH + r) * ROWSTRIDE + DIN] * (1.0f / 3.0f);
    #pragma unroll
    for (int j = 0; j < 4; j++) {
      const int c = col0 + j;
      float v = acc[i][j] + bias[c];
      if (EPI == 0)      C[(size_t)r * ldc + c] = v;
      else if (EPI == 1) C[(size_t)r * ldc + c] = tanhf(v);
      else               C[(size_t)r * ldc + c] += v * dscale;
    }
  }
}

// Fused GRU pointwise + fp32 output emission + next-state build.
// hcat_next[:, :512] = hcat_next[:, 512:] = new_h[:, :512]
__global__ __launch_bounds__(256) void gru_k(
    const float* __restrict__ gh, const float* __restrict__ gi,
    const float* __restrict__ hcat, float* __restrict__ hcat_next,
    float* __restrict__ out, int t)
{
  int idx = blockIdx.x * 256 + threadIdx.x;  // over 256*1024
  int b = idx >> 10, j = idx & 1023;
  size_t gb = (size_t)b * GSZ;
  float r = sigmoidf_(gi[gb + j]        + gh[gb + j]);
  float z = sigmoidf_(gi[gb + 1024 + j] + gh[gb + 1024 + j]);
  float n = tanhf   (gi[gb + 2048 + j] + r * gh[gb + 2048 + j]);
  float hv = hcat[(size_t)b * HID + j];
  float val = (1.f - z) * n + z * hv;
  // output 1: final new_h (overwritten each step; last step survives)
  out[(size_t)LSEQ * BATCH * LAT + (size_t)b * HID + j] = val;
  if (j < LAT) {
    out[((size_t)t * BATCH + b) * LAT + j] = val;   // output 0: ode_states_post[t]
    hcat_next[(size_t)b * HID + j]       = val;     // next y (ode state)
    hcat_next[(size_t)b * HID + LAT + j] = val;     // next gru state
  }
}

extern "C" void kernel_launch(void* const* d_in, const int* in_sizes, int n_in,
                              void* d_out, int out_size, void* d_ws, size_t ws_size,
                              hipStream_t stream)
{
  const float* data = (const float*)d_in[0];
  const float* w1   = (const float*)d_in[1];
  const float* b1   = (const float*)d_in[2];
  const float* w2   = (const float*)d_in[3];
  const float* b2   = (const float*)d_in[4];
  const float* wih  = (const float*)d_in[5];
  const float* bih  = (const float*)d_in[6];
  const float* whh  = (const float*)d_in[7];
  const float* bhh  = (const float*)d_in[8];
  float* out = (float*)d_out;

  float* ws    = (float*)d_ws;
  float* hcat0 = ws;                         // 256*1024
  float* hcat1 = hcat0 + BATCH * HID;        // 256*1024
  float* h1    = hcat1 + BATCH * HID;        // 256*1024
  float* gatesh = h1 + BATCH * HID;          // 256*3072
  float* gatesi = gatesh + (size_t)BATCH * GSZ; // 256*3072  (total ~9 MiB fp32)

  zero_k<<<dim3((BATCH * HID) / 256), 256, 0, stream>>>(hcat0, BATCH * HID);

  for (int t = 0; t < LSEQ; t++) {
    float* cur = (t & 1) ? hcat1 : hcat0;
    float* nxt = (t & 1) ? hcat0 : hcat1;
    for (int s = 0; s < 3; s++) {
      // h1 = tanh(y @ w1 + b1); y = cur[:, :512], lda=1024
      gemm_k<false, false, 1><<<dim3(1024 / 64, 4), 256, 0, stream>>>(
          cur, HID, w1, 1024, b1, h1, 1024, LAT, nullptr, 0);
      // y += (h1 @ w2 + b2) * dt/3
      gemm_k<false, false, 2><<<dim3(512 / 64, 4), 256, 0, stream>>>(
          h1, 1024, w2, 512, b2, cur, HID, 1024, data, t);
    }
    // gatesh = hcat @ whh^T + bhh
    gemm_k<false, true, 0><<<dim3(GSZ / 64, 4), 256, 0, stream>>>(
        cur, HID, whh, HID, bhh, gatesh, GSZ, HID, nullptr, 0);
    // gatesi = x_t @ wih^T + bih  (x_t = fp32 rows strided by 257 inside data)
    gemm_k<true, true, 0><<<dim3(GSZ / 64, 4), 256, 0, stream>>>(
        data + (size_t)t * BATCH * ROWSTRIDE, ROWSTRIDE, wih, DIN, bih, gatesi, GSZ, DIN, nullptr, 0);
    // GRU pointwise + outputs + next state
    gru_k<<<dim3((BATCH * HID) / 256), 256, 0, stream>>>(gatesh, gatesi, cur, nxt, out, t);
  }
}

// Round 4
// 7833.147 us; speedup vs baseline: 2.0228x; 2.0228x over previous
//
#include <hip/hip_runtime.h>

#define LSEQ 50
#define BATCH 256
#define DIN 256
#define LAT 512
#define HID 1024
#define ROWSTRIDE 257  // D_IN + 1 (dt channel)

typedef __attribute__((ext_vector_type(8))) short s16x8;
typedef __attribute__((ext_vector_type(8))) unsigned short u16x8;
typedef __attribute__((ext_vector_type(4))) float f32x4;
using u16 = unsigned short;

__device__ __forceinline__ u16 bfhi(float v) {
  union { float f; unsigned u; } a; a.f = v;
  return (u16)((a.u + 0x7FFFu + ((a.u >> 16) & 1u)) >> 16);
}
// v ~= hi + lo, each bf16; residual ~2^-17 relative
__device__ __forceinline__ void split2(float v, u16& h, u16& l) {
  u16 hu = bfhi(v);
  union { unsigned u; float f; } hf; hf.u = ((unsigned)hu) << 16;
  h = hu;
  l = bfhi(v - hf.f);
}
__device__ __forceinline__ float sigmoidf_(float x) { return 1.0f / (1.0f + __expf(-x)); }
__device__ __forceinline__ f32x4 mfma16(s16x8 a, s16x8 b, f32x4 c) {
  return __builtin_amdgcn_mfma_f32_16x16x32_bf16(a, b, c, 0, 0, 0);
}

// ---------- preprocessing ----------
// W[K][N] fp32 -> WT_hi[N][K], WT_lo[N][K] bf16 planes (transpose + split)
__global__ __launch_bounds__(256) void tsplit_k(const float* __restrict__ W,
    u16* __restrict__ Thi, u16* __restrict__ Tlo, int K, int N)
{
  __shared__ unsigned Ts[32][33];
  const int bk = blockIdx.x * 32, bn = blockIdx.y * 32;
  const int t = threadIdx.x;
  const int n_l = t & 31, k_l4 = (t >> 5) * 4;
  #pragma unroll
  for (int i = 0; i < 4; i++) {
    float v = W[(size_t)(bk + k_l4 + i) * N + bn + n_l];
    u16 h, l; split2(v, h, l);
    Ts[k_l4 + i][n_l] = ((unsigned)h << 16) | l;
  }
  __syncthreads();
  const int k_l = t & 31, n_l2 = t >> 5;
  #pragma unroll
  for (int i = 0; i < 4; i++) {
    int nn = n_l2 + 8 * i;
    unsigned u = Ts[k_l][nn];
    size_t o = (size_t)(bn + nn) * K + bk + k_l;
    Thi[o] = (u16)(u >> 16);
    Tlo[o] = (u16)(u & 0xFFFFu);
  }
}

// elementwise split (layout preserved); n = total/1024 blocks of 256 thr x 4
__global__ __launch_bounds__(256) void esplit_k(const float* __restrict__ W,
    u16* __restrict__ Phi, u16* __restrict__ Plo)
{
  size_t i4 = ((size_t)blockIdx.x * 256 + threadIdx.x) * 4;
  float4 v = *(const float4*)&W[i4];
  u16 h[4], l[4];
  split2(v.x, h[0], l[0]); split2(v.y, h[1], l[1]);
  split2(v.z, h[2], l[2]); split2(v.w, h[3], l[3]);
  *(ushort4*)&Phi[i4] = make_ushort4(h[0], h[1], h[2], h[3]);
  *(ushort4*)&Plo[i4] = make_ushort4(l[0], l[1], l[2], l[3]);
}

__global__ __launch_bounds__(256) void zero_init_k(float* __restrict__ cf,
    u16* __restrict__ chi, u16* __restrict__ clo)
{
  size_t i4 = ((size_t)blockIdx.x * 256 + threadIdx.x) * 4;
  *(float4*)&cf[i4] = make_float4(0.f, 0.f, 0.f, 0.f);
  *(ushort4*)&chi[i4] = make_ushort4(0, 0, 0, 0);
  *(ushort4*)&clo[i4] = make_ushort4(0, 0, 0, 0);
}

// ---------- MLP GEMM (MFMA, split-bf16) ----------
// C[M x N] = A[M x K] @ B[K x N]; A from activation planes (stride 1024),
// B from pre-split [N][K] planes. Block tile 64x64, 4 waves (2x2), wave 32x32.
// EPI 1: h1 planes = split(tanh(v + b1))
// EPI 2: curf += (v + b2)*dt/3 ; cur planes = split(new)
template<int EPI>
__global__ __launch_bounds__(256) void mlp_k(
    const u16* __restrict__ Ahi, const u16* __restrict__ Alo,
    const u16* __restrict__ Bhi, const u16* __restrict__ Blo, int ldb,
    const float* __restrict__ bias,
    u16* __restrict__ Ohi, u16* __restrict__ Olo,
    float* __restrict__ Cf,
    int K, const float* __restrict__ data, int t)
{
  __shared__ u16 Ah[64][40], Al[64][40], Bh[64][40], Bl[64][40];
  const int tid = threadIdx.x;
  const int bn = blockIdx.x * 64, bm = blockIdx.y * 64;
  const int srow = tid >> 2, skq = (tid & 3) * 8;
  const int lane = tid & 63, wave = tid >> 6;
  const int wm = (wave >> 1) * 32, wn = (wave & 1) * 32;
  const int lr = lane & 15, lq = lane >> 4;

  f32x4 acc[2][2] = {};
  for (int k0 = 0; k0 < K; k0 += 32) {
    __syncthreads();
    {
      size_t o = (size_t)(bm + srow) * 1024 + k0 + skq;
      *(u16x8*)&Ah[srow][skq] = *(const u16x8*)&Ahi[o];
      *(u16x8*)&Al[srow][skq] = *(const u16x8*)&Alo[o];
    }
    {
      size_t o = (size_t)(bn + srow) * ldb + k0 + skq;
      *(u16x8*)&Bh[srow][skq] = *(const u16x8*)&Bhi[o];
      *(u16x8*)&Bl[srow][skq] = *(const u16x8*)&Blo[o];
    }
    __syncthreads();
    s16x8 ah[2], al[2], bh[2], bl[2];
    #pragma unroll
    for (int i = 0; i < 2; i++) {
      ah[i] = *(const s16x8*)&Ah[wm + i * 16 + lr][lq * 8];
      al[i] = *(const s16x8*)&Al[wm + i * 16 + lr][lq * 8];
      bh[i] = *(const s16x8*)&Bh[wn + i * 16 + lr][lq * 8];
      bl[i] = *(const s16x8*)&Bl[wn + i * 16 + lr][lq * 8];
    }
    #pragma unroll
    for (int i = 0; i < 2; i++)
      #pragma unroll
      for (int j = 0; j < 2; j++) {
        acc[i][j] = mfma16(ah[i], bh[j], acc[i][j]);
        acc[i][j] = mfma16(ah[i], bl[j], acc[i][j]);
        acc[i][j] = mfma16(al[i], bh[j], acc[i][j]);
      }
  }
  #pragma unroll
  for (int i = 0; i < 2; i++)
    #pragma unroll
    for (int j = 0; j < 2; j++)
      #pragma unroll
      for (int r = 0; r < 4; r++) {
        const int row = bm + wm + i * 16 + lq * 4 + r;
        const int col = bn + wn + j * 16 + lr;
        float v = acc[i][j][r] + bias[col];
        if (EPI == 1) {
          float h1 = tanhf(v);
          u16 h, l; split2(h1, h, l);
          size_t o = (size_t)row * 1024 + col;
          Ohi[o] = h; Olo[o] = l;
        } else {
          float dt3 = data[(size_t)(t * BATCH + row) * ROWSTRIDE + DIN] * (1.0f / 3.0f);
          size_t o = (size_t)row * 1024 + col;
          float y = Cf[o] + v * dt3;
          Cf[o] = y;
          u16 h, l; split2(y, h, l);
          Ohi[o] = h; Olo[o] = l;
        }
      }
}

// ---------- fused GRU: gh(K=1024) + gi(K=256) + pointwise + outputs ----------
template<bool PLANES>
__global__ __launch_bounds__(256) void gru_fused_k(
    const u16* __restrict__ Ahi, const u16* __restrict__ Alo,   // hcat planes [256][1024]
    const float* __restrict__ curf,                             // hcat fp32
    const float* __restrict__ whh, const u16* __restrict__ whh_hi, const u16* __restrict__ whh_lo,
    const float* __restrict__ wih, const u16* __restrict__ wih_hi, const u16* __restrict__ wih_lo,
    const float* __restrict__ bih, const float* __restrict__ bhh,
    const float* __restrict__ data, int t,
    float* __restrict__ nxtf, u16* __restrict__ nxt_hi, u16* __restrict__ nxt_lo,
    float* __restrict__ out)
{
  __shared__ u16 Ah[64][40], Al[64][40];
  __shared__ u16 Bh[3][64][40], Bl[3][64][40];
  const int tid = threadIdx.x;
  const int bn = blockIdx.x * 64, bm = blockIdx.y * 64;
  const int srow = tid >> 2, skq = (tid & 3) * 8;
  const int lane = tid & 63, wave = tid >> 6;
  const int wm = (wave >> 1) * 32, wn = (wave & 1) * 32;
  const int lr = lane & 15, lq = lane >> 4;

  f32x4 aR[2][2] = {}, aZ[2][2] = {}, aNh[2][2] = {}, aNi[2][2] = {};

  // phase 0: gh accumulation, A = hcat planes, B = whh rows, K = 1024
  for (int k0 = 0; k0 < 1024; k0 += 32) {
    __syncthreads();
    {
      size_t o = (size_t)(bm + srow) * 1024 + k0 + skq;
      *(u16x8*)&Ah[srow][skq] = *(const u16x8*)&Ahi[o];
      *(u16x8*)&Al[srow][skq] = *(const u16x8*)&Alo[o];
    }
    #pragma unroll
    for (int g = 0; g < 3; g++) {
      size_t r = (size_t)(g * 1024 + bn + srow);
      if (PLANES) {
        size_t o = r * 1024 + k0 + skq;
        *(u16x8*)&Bh[g][srow][skq] = *(const u16x8*)&whh_hi[o];
        *(u16x8*)&Bl[g][srow][skq] = *(const u16x8*)&whh_lo[o];
      } else {
        const float* p = &whh[r * 1024 + k0 + skq];
        float4 u = *(const float4*)p, v = *(const float4*)(p + 4);
        float vv[8] = {u.x, u.y, u.z, u.w, v.x, v.y, v.z, v.w};
        u16x8 h8, l8;
        #pragma unroll
        for (int i = 0; i < 8; i++) { u16 h, l; split2(vv[i], h, l); h8[i] = h; l8[i] = l; }
        *(u16x8*)&Bh[g][srow][skq] = h8;
        *(u16x8*)&Bl[g][srow][skq] = l8;
      }
    }
    __syncthreads();
    s16x8 ah[2], al[2];
    #pragma unroll
    for (int i = 0; i < 2; i++) {
      ah[i] = *(const s16x8*)&Ah[wm + i * 16 + lr][lq * 8];
      al[i] = *(const s16x8*)&Al[wm + i * 16 + lr][lq * 8];
    }
    #pragma unroll
    for (int g = 0; g < 3; g++) {
      #pragma unroll
      for (int j = 0; j < 2; j++) {
        s16x8 bh = *(const s16x8*)&Bh[g][wn + j * 16 + lr][lq * 8];
        s16x8 bl = *(const s16x8*)&Bl[g][wn + j * 16 + lr][lq * 8];
        #pragma unroll
        for (int i = 0; i < 2; i++) {
          f32x4 c = (g == 0) ? aR[i][j] : (g == 1) ? aZ[i][j] : aNh[i][j];
          c = mfma16(ah[i], bh, c);
          c = mfma16(ah[i], bl, c);
          c = mfma16(al[i], bh, c);
          if (g == 0) aR[i][j] = c; else if (g == 1) aZ[i][j] = c; else aNh[i][j] = c;
        }
      }
    }
  }
  // phase 1: gi accumulation, A = x_t (strided fp32, split on the fly), K = 256
  for (int k0 = 0; k0 < 256; k0 += 32) {
    __syncthreads();
    {
      const float* p = &data[(size_t)(t * BATCH + bm + srow) * ROWSTRIDE + k0 + skq];
      u16x8 h8, l8;
      #pragma unroll
      for (int i = 0; i < 8; i++) { u16 h, l; split2(p[i], h, l); h8[i] = h; l8[i] = l; }
      *(u16x8*)&Ah[srow][skq] = h8;
      *(u16x8*)&Al[srow][skq] = l8;
    }
    #pragma unroll
    for (int g = 0; g < 3; g++) {
      size_t r = (size_t)(g * 1024 + bn + srow);
      if (PLANES) {
        size_t o = r * 256 + k0 + skq;
        *(u16x8*)&Bh[g][srow][skq] = *(const u16x8*)&wih_hi[o];
        *(u16x8*)&Bl[g][srow][skq] = *(const u16x8*)&wih_lo[o];
      } else {
        const float* p = &wih[r * 256 + k0 + skq];
        float4 u = *(const float4*)p, v = *(const float4*)(p + 4);
        float vv[8] = {u.x, u.y, u.z, u.w, v.x, v.y, v.z, v.w};
        u16x8 h8, l8;
        #pragma unroll
        for (int i = 0; i < 8; i++) { u16 h, l; split2(vv[i], h, l); h8[i] = h; l8[i] = l; }
        *(u16x8*)&Bh[g][srow][skq] = h8;
        *(u16x8*)&Bl[g][srow][skq] = l8;
      }
    }
    __syncthreads();
    s16x8 ah[2], al[2];
    #pragma unroll
    for (int i = 0; i < 2; i++) {
      ah[i] = *(const s16x8*)&Ah[wm + i * 16 + lr][lq * 8];
      al[i] = *(const s16x8*)&Al[wm + i * 16 + lr][lq * 8];
    }
    #pragma unroll
    for (int g = 0; g < 3; g++) {
      #pragma unroll
      for (int j = 0; j < 2; j++) {
        s16x8 bh = *(const s16x8*)&Bh[g][wn + j * 16 + lr][lq * 8];
        s16x8 bl = *(const s16x8*)&Bl[g][wn + j * 16 + lr][lq * 8];
        #pragma unroll
        for (int i = 0; i < 2; i++) {
          f32x4 c = (g == 0) ? aR[i][j] : (g == 1) ? aZ[i][j] : aNi[i][j];
          c = mfma16(ah[i], bh, c);
          c = mfma16(ah[i], bl, c);
          c = mfma16(al[i], bh, c);
          if (g == 0) aR[i][j] = c; else if (g == 1) aZ[i][j] = c; else aNi[i][j] = c;
        }
      }
    }
  }
  // epilogue: GRU pointwise, outputs, next state
  #pragma unroll
  for (int i = 0; i < 2; i++)
    #pragma unroll
    for (int j = 0; j < 2; j++)
      #pragma unroll
      for (int r4 = 0; r4 < 4; r4++) {
        const int row = bm + wm + i * 16 + lq * 4 + r4;
        const int jg = bn + wn + j * 16 + lr;  // 0..1023
        float rr = sigmoidf_(aR[i][j][r4] + bih[jg] + bhh[jg]);
        float zz = sigmoidf_(aZ[i][j][r4] + bih[1024 + jg] + bhh[1024 + jg]);
        float nn = tanhf(aNi[i][j][r4] + bih[2048 + jg] + rr * (aNh[i][j][r4] + bhh[2048 + jg]));
        float hv = curf[(size_t)row * 1024 + jg];
        float val = (1.f - zz) * nn + zz * hv;
        out[(size_t)LSEQ * BATCH * LAT + (size_t)row * 1024 + jg] = val;  // output 1
        if (jg < LAT) {
          out[((size_t)t * BATCH + row) * LAT + jg] = val;               // output 0
          u16 h, l; split2(val, h, l);
          size_t o = (size_t)row * 1024 + jg;
          nxtf[o] = val;          nxtf[o + LAT] = val;
          nxt_hi[o] = h;          nxt_hi[o + LAT] = h;
          nxt_lo[o] = l;          nxt_lo[o + LAT] = l;
        }
      }
}

extern "C" void kernel_launch(void* const* d_in, const int* in_sizes, int n_in,
                              void* d_out, int out_size, void* d_ws, size_t ws_size,
                              hipStream_t stream)
{
  const float* data = (const float*)d_in[0];
  const float* w1   = (const float*)d_in[1];
  const float* b1   = (const float*)d_in[2];
  const float* w2   = (const float*)d_in[3];
  const float* b2   = (const float*)d_in[4];
  const float* wih  = (const float*)d_in[5];
  const float* bih  = (const float*)d_in[6];
  const float* whh  = (const float*)d_in[7];
  const float* bhh  = (const float*)d_in[8];
  float* out = (float*)d_out;

  char* w = (char*)d_ws;
  auto alloc = [&](size_t bytes) { char* p = w; w += bytes; return p; };
  u16*   w1t_hi = (u16*)alloc(512 * 1024 * 2);   // [1024][512]
  u16*   w1t_lo = (u16*)alloc(512 * 1024 * 2);
  u16*   w2t_hi = (u16*)alloc(512 * 1024 * 2);   // [512][1024]
  u16*   w2t_lo = (u16*)alloc(512 * 1024 * 2);
  float* cur0f  = (float*)alloc(BATCH * HID * 4);
  float* cur1f  = (float*)alloc(BATCH * HID * 4);
  u16*   c0hi   = (u16*)alloc(BATCH * HID * 2);
  u16*   c0lo   = (u16*)alloc(BATCH * HID * 2);
  u16*   c1hi   = (u16*)alloc(BATCH * HID * 2);
  u16*   c1lo   = (u16*)alloc(BATCH * HID * 2);
  u16*   h1hi   = (u16*)alloc(BATCH * HID * 2);
  u16*   h1lo   = (u16*)alloc(BATCH * HID * 2);
  size_t base = (size_t)(w - (char*)d_ws);
  size_t need_opt = base + (size_t)(3072 * 1024 + 3072 * 256) * 2 * 2;
  bool planes = ws_size >= need_opt;
  u16 *whh_hi = nullptr, *whh_lo = nullptr, *wih_hi = nullptr, *wih_lo = nullptr;
  if (planes) {
    whh_hi = (u16*)alloc((size_t)3072 * 1024 * 2);
    whh_lo = (u16*)alloc((size_t)3072 * 1024 * 2);
    wih_hi = (u16*)alloc((size_t)3072 * 256 * 2);
    wih_lo = (u16*)alloc((size_t)3072 * 256 * 2);
  }

  // preprocess
  tsplit_k<<<dim3(512 / 32, 1024 / 32), 256, 0, stream>>>(w1, w1t_hi, w1t_lo, 512, 1024);
  tsplit_k<<<dim3(1024 / 32, 512 / 32), 256, 0, stream>>>(w2, w2t_hi, w2t_lo, 1024, 512);
  if (planes) {
    esplit_k<<<dim3((3072 * 1024) / 1024), 256, 0, stream>>>(whh, whh_hi, whh_lo);
    esplit_k<<<dim3((3072 * 256) / 1024), 256, 0, stream>>>(wih, wih_hi, wih_lo);
  }
  zero_init_k<<<dim3((BATCH * HID) / 1024), 256, 0, stream>>>(cur0f, c0hi, c0lo);

  for (int t = 0; t < LSEQ; t++) {
    float* curf = (t & 1) ? cur1f : cur0f;
    float* nxtf = (t & 1) ? cur0f : cur1f;
    u16 *chi = (t & 1) ? c1hi : c0hi, *clo = (t & 1) ? c1lo : c0lo;
    u16 *nhi = (t & 1) ? c0hi : c1hi, *nlo = (t & 1) ? c0lo : c1lo;
    for (int s = 0; s < 3; s++) {
      mlp_k<1><<<dim3(16, 4), 256, 0, stream>>>(chi, clo, w1t_hi, w1t_lo, 512, b1,
                                                h1hi, h1lo, nullptr, 512, nullptr, 0);
      mlp_k<2><<<dim3(8, 4), 256, 0, stream>>>(h1hi, h1lo, w2t_hi, w2t_lo, 1024, b2,
                                               chi, clo, curf, 1024, data, t);
    }
    if (planes)
      gru_fused_k<true><<<dim3(16, 4), 256, 0, stream>>>(chi, clo, curf,
          whh, whh_hi, whh_lo, wih, wih_hi, wih_lo, bih, bhh, data, t,
          nxtf, nhi, nlo, out);
    else
      gru_fused_k<false><<<dim3(16, 4), 256, 0, stream>>>(chi, clo, curf,
          whh, whh_hi, whh_lo, wih, wih_hi, wih_lo, bih, bhh, data, t,
          nxtf, nhi, nlo, out);
  }
}